// Round 2
// baseline (515.456 us; speedup 1.0000x reference)
//
#include <hip/hip_runtime.h>
#include <math.h>

// Shapes fixed by reference setup_inputs()
constexpr int B  = 8;
constexpr int H  = 16;
constexpr int NT = 512;
constexpr int NV = 576;
constexpr int TILE = 64;
constexpr int M  = NT * NV;            // elements per (b,h) plane = 294912
constexpr int M4 = M / 4;              // float4 per plane = 73728
constexpr int OUT4_PER_TENSOR = B * M4; // 589824 float4 outputs per tensor
constexpr float INV_H2 = 1.0f / (float)(H * H);

// ws layout (floats): P[4][B*M]  (order: Pt0, Pv0, Pt1, Pv1 — unscaled H-sums)
// then text_acc[2][B][NT], vis_acc[2][B][NV]
constexpr size_t P_FLOATS = (size_t)4 * B * M;      // 9437184
constexpr int TEXT_N = 2 * B * NT;                  // 8192
constexpr int VIS_N  = 2 * B * NV;                  // 9216

__global__ void zero_ws_kernel(float* __restrict__ ws, int n) {
    int i = blockIdx.x * blockDim.x + threadIdx.x;
    if (i < n) ws[i] = 0.0f;
}

// Pass 1: P[b, m] = sum_h X[b, h, m], one float4 per thread.
// Wave reads 1 KB contiguous per load instruction; 16 independent loads/thread.
__global__ __launch_bounds__(256) void mean_kernel(
    const float4* __restrict__ x0, const float4* __restrict__ x1,
    const float4* __restrict__ x2, const float4* __restrict__ x3,
    float4* __restrict__ p)   // p: [4][B*M4]
{
    const int o = blockIdx.x * blockDim.x + threadIdx.x;  // 0..OUT4_PER_TENSOR-1
    const int t = blockIdx.y;                             // tensor 0..3
    const float4* __restrict__ x = (t == 0) ? x0 : (t == 1) ? x1 : (t == 2) ? x2 : x3;

    const int b  = o / M4;
    const int m4 = o - b * M4;
    const float4* __restrict__ src = x + (size_t)b * H * M4 + m4;

    // two partial sums to shorten the fp dependency chain
    float4 s0 = make_float4(0.f, 0.f, 0.f, 0.f);
    float4 s1 = make_float4(0.f, 0.f, 0.f, 0.f);
#pragma unroll
    for (int h = 0; h < H; h += 2) {
        const float4 a = src[(size_t)h * M4];
        const float4 c = src[(size_t)(h + 1) * M4];
        s0.x += a.x; s0.y += a.y; s0.z += a.z; s0.w += a.w;
        s1.x += c.x; s1.y += c.y; s1.z += c.z; s1.w += c.w;
    }
    s0.x += s1.x; s0.y += s1.y; s0.z += s1.z; s0.w += s1.w;
    p[(size_t)t * OUT4_PER_TENSOR + o] = s0;
}

// Pass 2: per (k-tile, i-tile, b+B*layer) block, read 64x64 tiles of Pt and Pv
// (L3-resident), transpose Pv via LDS, Q = Pt .* Pv^T, reduce rows -> text,
// cols -> vision, atomic-accumulate to global.
__global__ __launch_bounds__(256) void diag_kernel(
    const float* __restrict__ P,     // [4][B*M]
    float* __restrict__ text_acc,    // [2][B][NT]
    float* __restrict__ vis_acc)     // [2][B][NV]
{
    const int ktile = blockIdx.x;   // 0..NV/TILE-1
    const int itile = blockIdx.y;   // 0..NT/TILE-1
    const int bz    = blockIdx.z;   // 0..2*B-1
    const int b     = bz & (B - 1);
    const int layer = bz >> 3;

    const float* __restrict__ Pt = P + (size_t)(2 * layer) * B * M + (size_t)b * M;
    const float* __restrict__ Pv = P + (size_t)(2 * layer + 1) * B * M + (size_t)b * M;

    const int tid = threadIdx.x;
    const int c = tid & 15;   // column group: floats 4c..4c+3
    const int g = tid >> 4;   // row group: rows g, g+16, g+32, g+48

    const int i0 = itile * TILE;
    const int k0 = ktile * TILE;

    float4 tacc[4];
    float4 vacc[4];
#pragma unroll
    for (int r = 0; r < 4; ++r) {
        const int row = g + 16 * r;
        tacc[r] = *(const float4*)(Pt + (size_t)(i0 + row) * NV + k0 + 4 * c);
        vacc[r] = *(const float4*)(Pv + (size_t)(k0 + row) * NT + i0 + 4 * c);
    }

    // LDS transpose of the Pv tile. Stride 65 -> 2-way bank alias (free, m136).
    __shared__ float vlds[TILE * 65];
    __shared__ float rowsum[TILE];
    __shared__ float colsum[TILE];

    if (tid < TILE) {
        rowsum[tid] = 0.0f;
        colsum[tid] = 0.0f;
    }

#pragma unroll
    for (int r = 0; r < 4; ++r) {
        const int kk = g + 16 * r;          // Pv row (NV dim within tile)
        float* p = &vlds[kk * 65 + 4 * c];  // cols ii = 4c..4c+3 (NT dim)
        p[0] = vacc[r].x; p[1] = vacc[r].y; p[2] = vacc[r].z; p[3] = vacc[r].w;
    }
    __syncthreads();

    float colpart[4] = {0.f, 0.f, 0.f, 0.f};
#pragma unroll
    for (int r = 0; r < 4; ++r) {
        const int ii = g + 16 * r;
        const float tq[4] = {tacc[r].x, tacc[r].y, tacc[r].z, tacc[r].w};
        float rp = 0.f;
#pragma unroll
        for (int j = 0; j < 4; ++j) {
            const int kk = 4 * c + j;
            const float q = tq[j] * vlds[kk * 65 + ii];
            rp += q;
            colpart[j] += q;
        }
        atomicAdd(&rowsum[ii], rp);
    }
#pragma unroll
    for (int j = 0; j < 4; ++j) {
        atomicAdd(&colsum[4 * c + j], colpart[j]);
    }
    __syncthreads();

    const int lb = layer * B + b;
    if (tid < TILE) {
        atomicAdd(&text_acc[(size_t)lb * NT + i0 + tid], rowsum[tid] * INV_H2);
    } else if (tid < 2 * TILE) {
        const int kk = tid - TILE;
        atomicAdd(&vis_acc[(size_t)lb * NV + k0 + kk], colsum[kk] * INV_H2);
    }
}

// Single block: weighted sum of -log(clip(x)) over all diag entries.
__global__ __launch_bounds__(256) void finalize_kernel(
    const float* __restrict__ text_acc,
    const float* __restrict__ vis_acc,
    float* __restrict__ out)
{
    const int tid = threadIdx.x;
    const float wt = 0.25f / (float)(B * NT);
    const float wv = 0.25f / (float)(B * NV);

    float s = 0.f;
    for (int i = tid; i < TEXT_N; i += 256) {
        float x = text_acc[i];
        x = fminf(fmaxf(x, 1e-8f), 1.0f);
        s += -logf(x) * wt;
    }
    for (int i = tid; i < VIS_N; i += 256) {
        float x = vis_acc[i];
        x = fminf(fmaxf(x, 1e-8f), 1.0f);
        s += -logf(x) * wv;
    }

#pragma unroll
    for (int off = 32; off > 0; off >>= 1) s += __shfl_down(s, off, 64);

    __shared__ float wsum[4];
    if ((tid & 63) == 0) wsum[tid >> 6] = s;
    __syncthreads();
    if (tid == 0) out[0] = wsum[0] + wsum[1] + wsum[2] + wsum[3];
}

extern "C" void kernel_launch(void* const* d_in, const int* in_sizes, int n_in,
                              void* d_out, int out_size, void* d_ws, size_t ws_size,
                              hipStream_t stream) {
    const float4* t0 = (const float4*)d_in[0];
    const float4* v0 = (const float4*)d_in[1];
    const float4* t1 = (const float4*)d_in[2];
    const float4* v1 = (const float4*)d_in[3];

    float* P        = (float*)d_ws;                 // 4*B*M floats = 37.75 MB
    float* text_acc = P + P_FLOATS;
    float* vis_acc  = text_acc + TEXT_N;
    float* out      = (float*)d_out;

    // 1. zero the diag accumulators (ws is poisoned to 0xAA each launch)
    {
        const int n = TEXT_N + VIS_N;
        zero_ws_kernel<<<(n + 255) / 256, 256, 0, stream>>>(text_acc, n);
    }

    // 2. H-sum: fully-contiguous streaming reduction (the HBM-heavy pass)
    {
        dim3 grid(OUT4_PER_TENSOR / 256, 4);  // (2304, 4)
        mean_kernel<<<grid, 256, 0, stream>>>(t0, v0, t1, v1, (float4*)P);
    }

    // 3. diag products + row/col reduction (L3-resident inputs)
    {
        dim3 grid(NV / TILE, NT / TILE, 2 * B);  // (9, 8, 16)
        diag_kernel<<<grid, 256, 0, stream>>>(P, text_acc, vis_acc);
    }

    // 4. clip/log/mean -> scalar
    finalize_kernel<<<1, 256, 0, stream>>>(text_acc, vis_acc, out);
}